// Round 6
// baseline (771.413 us; speedup 1.0000x reference)
//
#include <hip/hip_runtime.h>
#include <hip/hip_bf16.h>
#include <math.h>

#define B_N 32
#define S_LEN 4096
#define NTOK (B_N * S_LEN)   // 131072
#define EMB 256
#define NCODE 512
#define WB_STRIDE 98304      // per-batch weight entries (bf16)

typedef __attribute__((ext_vector_type(8))) short short8v;   // 8 bf16 = 4 VGPRs
typedef __attribute__((ext_vector_type(4))) float float4v;
typedef __attribute__((ext_vector_type(2))) float float2v;

__device__ inline ushort f2b(float v) {
    union { __hip_bfloat16 h; ushort u; } cv;
    cv.h = __float2bfloat16(v);   // RNE
    return cv.u;
}
__device__ inline float b2f(ushort u) {
    union { ushort u2[2]; float f; } cv;
    cv.u2[0] = 0; cv.u2[1] = u;
    return cv.f;
}

// ---- ws layout (bytes) ----
constexpr size_t WSB_W   = 0;         // ushort[3145728] generated weights (bf16)
constexpr size_t WSB_CB  = 6291456;   // ushort[131072] codebook bf16
constexpr size_t WSB_CBN = 6553600;   // float[512] codebook sq-norms
constexpr size_t WSB_ACC = 6555648;   // float[513]: [0]=sse, [1..512]=hist
constexpr size_t WSB_IDX = 6558720;   // int[131072] per-token code index

// ---- out layout (floats) ----
constexpr size_t OUT_SCAL = 33554432; // loss, perplexity
constexpr size_t OUT_XR   = 33554434; // x_recon (8B-aligned only -> float2 stores)

// ================= weight generation (all 6 layers, one launch) =================
struct WgenP {
    const float* bw[6]; const float* aw[6]; const float* ab[6];
    int loff[6]; int bstart[7];
};

__global__ __launch_bounds__(256)
void wgen_all(WgenP p, const float* __restrict__ adapt, ushort* __restrict__ wout)
{
    __shared__ float ad[B_N * 64];
    int tid = threadIdx.x;
    for (int i = tid; i < B_N * 64; i += 256) ad[i] = adapt[i];
    __syncthreads();
    int blk = blockIdx.x;
    int l = 0;
    while (l < 5 && blk >= p.bstart[l + 1]) ++l;
    int r = (blk - p.bstart[l]) * 256 + tid;

    float a[64];
    const float4* aw4 = reinterpret_cast<const float4*>(p.aw[l] + (size_t)r * 64);
#pragma unroll
    for (int q = 0; q < 16; ++q) {
        float4 v = aw4[q];
        a[4*q] = v.x; a[4*q+1] = v.y; a[4*q+2] = v.z; a[4*q+3] = v.w;
    }
    float abr = p.ab[l][r], bwr = p.bw[l][r];
    int loff = p.loff[l];
    for (int b2 = 0; b2 < B_N; ++b2) {
        const float* adp = &ad[b2 * 64];
        float s0 = 0.f, s1 = 0.f, s2 = 0.f, s3 = 0.f;
#pragma unroll
        for (int j = 0; j < 64; j += 4) {
            s0 += a[j]   * adp[j];
            s1 += a[j+1] * adp[j+1];
            s2 += a[j+2] * adp[j+2];
            s3 += a[j+3] * adp[j+3];
        }
        float s = ((s0 + s1) + (s2 + s3)) + abr;
        wout[(size_t)b2 * WB_STRIDE + loff + r] = f2b(bwr + s);
    }
}

// ================= codebook prep: norms (fp32) + bf16 copy =================
__global__ __launch_bounds__(256)
void cbprep_kernel(const float* __restrict__ cb, float* __restrict__ cbn,
                   ushort* __restrict__ cbbf)
{
    int c = blockIdx.x * 256 + threadIdx.x;
    if (c >= NCODE) return;
    const float4* c4 = reinterpret_cast<const float4*>(cb) + (size_t)c * 64;
    ushort4* o4 = reinterpret_cast<ushort4*>(cbbf) + (size_t)c * 64;
    float s = 0.f;
#pragma unroll 8
    for (int q = 0; q < 64; ++q) {
        float4 v = c4[q];
        s += v.x*v.x + v.y*v.y + v.z*v.z + v.w*v.w;
        o4[q] = make_ushort4(f2b(v.x), f2b(v.y), f2b(v.z), f2b(v.w));
    }
    cbn[c] = s;
}

// ================= fused encoder + VQ =================
// 64 tokens/block, 4 waves. Waves split output features per layer (weights
// read directly from L2). Intermediates live in LDS bf16.
// VQ reads codebook B-fragments DIRECTLY from L2 (no LDS staging, no barriers
// in the 32-tile argmin loop) -> compiler software-pipelines loads under MFMA.
__global__ __launch_bounds__(256)
void enc_vq(const float* __restrict__ x, const ushort* __restrict__ wbf,
            const float* __restrict__ bb0, const float* __restrict__ bb1,
            const float* __restrict__ bb2,
            const ushort* __restrict__ cbbf, const float* __restrict__ cbf,
            const float* __restrict__ cbn,
            float* __restrict__ zq, int* __restrict__ idxg, float* __restrict__ accg)
{
    __shared__ __align__(16) ushort zbuf[64 * 264];   // z bf16 [64][264]
    __shared__ __align__(16) ushort regA[64 * 136];   // xbuf[64][136] -> h1[64][136]
    __shared__ __align__(16) ushort regB[64 * 72];    // h0 [64][72]
    __shared__ float scbn[NCODE];
    __shared__ int   midx[64];
    __shared__ float red[256];

    const int tid = threadIdx.x;
    const int b = blockIdx.y, s0 = blockIdx.x * 64;
    const size_t tok0 = (size_t)b * S_LEN + s0;
    const int lane = tid & 63, w = tid >> 6, r16 = lane & 15, g = lane >> 4;

    for (int i = tid; i < NCODE; i += 256) scbn[i] = cbn[i];

    { // stage x fp32 -> bf16 LDS [64][136]
        const float4* x4 = reinterpret_cast<const float4*>(x) + tok0 * 32;
#pragma unroll
        for (int it = 0; it < 8; ++it) {
            int idx = tid + it * 256;
            int t = idx >> 5, k4 = idx & 31;
            float4 v = x4[(size_t)t * 32 + k4];
            *reinterpret_cast<ushort4*>(&regA[t * 136 + 4 * k4]) =
                make_ushort4(f2b(v.x), f2b(v.y), f2b(v.z), f2b(v.w));
        }
    }
    __syncthreads();

    const ushort* wb = wbf + (size_t)b * WB_STRIDE;

    // ---- e0: 128 -> 64, relu; wave owns cols [w*16, w*16+16)
    {
        const ushort* w0 = wb;                       // loff 0
        short8v bf[4];
#pragma unroll
        for (int ks = 0; ks < 4; ++ks)
            bf[ks] = *reinterpret_cast<const short8v*>(
                w0 + (size_t)(w*16 + r16) * 128 + ks*32 + g*8);
        float bias = bb0[w*16 + r16];
#pragma unroll
        for (int tt = 0; tt < 4; ++tt) {
            float4v acc = (float4v){0.f, 0.f, 0.f, 0.f};
#pragma unroll
            for (int ks = 0; ks < 4; ++ks) {
                short8v a = *reinterpret_cast<const short8v*>(
                    &regA[(tt*16 + r16) * 136 + ks*32 + g*8]);
                acc = __builtin_amdgcn_mfma_f32_16x16x32_bf16(a, bf[ks], acc, 0, 0, 0);
            }
#pragma unroll
            for (int reg = 0; reg < 4; ++reg)
                regB[(tt*16 + g*4 + reg) * 72 + w*16 + r16] =
                    f2b(fmaxf(acc[reg] + bias, 0.f));
        }
    }
    __syncthreads();

    // ---- e1: 64 -> 128, relu; wave cols [w*32, +32); h1 -> regA
    {
        const ushort* w1 = wb + 8192;
#pragma unroll
        for (int nt = 0; nt < 2; ++nt) {
            int col0 = w*32 + nt*16;
            float bias = bb1[col0 + r16];
            short8v bf[2];
#pragma unroll
            for (int ks = 0; ks < 2; ++ks)
                bf[ks] = *reinterpret_cast<const short8v*>(
                    w1 + (size_t)(col0 + r16) * 64 + ks*32 + g*8);
#pragma unroll
            for (int tt = 0; tt < 4; ++tt) {
                float4v acc = (float4v){0.f, 0.f, 0.f, 0.f};
#pragma unroll
                for (int ks = 0; ks < 2; ++ks) {
                    short8v a = *reinterpret_cast<const short8v*>(
                        &regB[(tt*16 + r16) * 72 + ks*32 + g*8]);
                    acc = __builtin_amdgcn_mfma_f32_16x16x32_bf16(a, bf[ks], acc, 0, 0, 0);
                }
#pragma unroll
                for (int reg = 0; reg < 4; ++reg)
                    regA[(tt*16 + g*4 + reg) * 136 + col0 + r16] =
                        f2b(fmaxf(acc[reg] + bias, 0.f));
            }
        }
    }
    __syncthreads();

    // ---- e2: 128 -> 256, none; wave cols [w*64, +64); z -> zbuf bf16
    {
        const ushort* w2 = wb + 16384;
#pragma unroll
        for (int nt = 0; nt < 4; ++nt) {
            int col0 = w*64 + nt*16;
            float bias = bb2[col0 + r16];
            short8v bf[4];
#pragma unroll
            for (int ks = 0; ks < 4; ++ks)
                bf[ks] = *reinterpret_cast<const short8v*>(
                    w2 + (size_t)(col0 + r16) * 128 + ks*32 + g*8);
#pragma unroll
            for (int tt = 0; tt < 4; ++tt) {
                float4v acc = (float4v){0.f, 0.f, 0.f, 0.f};
#pragma unroll
                for (int ks = 0; ks < 4; ++ks) {
                    short8v a = *reinterpret_cast<const short8v*>(
                        &regA[(tt*16 + r16) * 136 + ks*32 + g*8]);
                    acc = __builtin_amdgcn_mfma_f32_16x16x32_bf16(a, bf[ks], acc, 0, 0, 0);
                }
#pragma unroll
                for (int reg = 0; reg < 4; ++reg)
                    zbuf[(tt*16 + g*4 + reg) * 264 + col0 + r16] = f2b(acc[reg] + bias);
            }
        }
    }
    __syncthreads();   // zbuf complete

    // ---- VQ: wave owns tokens [w*16, +16); argmin over 512 codes.
    // B-fragments straight from L2 (codebook = 256 KB, cache-resident).
    // No barriers: loads for tile ct+1 overlap MFMAs of tile ct.
    short8v az[8];
#pragma unroll
    for (int ks = 0; ks < 8; ++ks)
        az[ks] = *reinterpret_cast<const short8v*>(
            &zbuf[(w*16 + r16) * 264 + ks*32 + g*8]);

    float mv[4] = {1e30f, 1e30f, 1e30f, 1e30f};
    int   mi[4] = {0, 0, 0, 0};

#pragma unroll 4
    for (int ct = 0; ct < 32; ++ct) {
        const int c0 = ct*16 + r16;                  // code = D col (lane&15)
        const ushort* rp = cbbf + (size_t)c0 * 256 + g*8;
        short8v bf[8];
#pragma unroll
        for (int ks = 0; ks < 8; ++ks)
            bf[ks] = *reinterpret_cast<const short8v*>(rp + ks*32);
        float4v d0 = (float4v){0.f, 0.f, 0.f, 0.f};
        float4v d1 = (float4v){0.f, 0.f, 0.f, 0.f};
#pragma unroll
        for (int ks = 0; ks < 8; ks += 2) {          // two chains: break dep
            d0 = __builtin_amdgcn_mfma_f32_16x16x32_bf16(az[ks],   bf[ks],   d0, 0, 0, 0);
            d1 = __builtin_amdgcn_mfma_f32_16x16x32_bf16(az[ks+1], bf[ks+1], d1, 0, 0, 0);
        }
        float cn = scbn[c0];
#pragma unroll
        for (int reg = 0; reg < 4; ++reg) {
            float dd = cn - 2.0f * (d0[reg] + d1[reg]);
            if (dd < mv[reg]) { mv[reg] = dd; mi[reg] = c0; }
        }
    }
    // butterfly over 16 code-lanes; lex (val, idx) min == first-index argmin
#pragma unroll
    for (int m = 1; m <= 8; m <<= 1) {
#pragma unroll
        for (int reg = 0; reg < 4; ++reg) {
            float ov = __shfl_xor(mv[reg], m);
            int   oi = __shfl_xor(mi[reg], m);
            if (ov < mv[reg] || (ov == mv[reg] && oi < mi[reg])) {
                mv[reg] = ov; mi[reg] = oi;
            }
        }
    }
    if (r16 == 0) {
#pragma unroll
        for (int reg = 0; reg < 4; ++reg) midx[w*16 + g*4 + reg] = mi[reg];
    }
    __syncthreads();
    if (tid < 64) {
        idxg[tok0 + tid] = midx[tid];
        atomicAdd(&accg[1 + midx[tid]], 1.0f);
    }

    // ---- epilogue: z_q = z + (q - z) (z from bf16 zbuf), sse accumulate
    float lsse = 0.f;
    float4v* zq4 = reinterpret_cast<float4v*>(zq) + tok0 * 64;
    const float4* cf4 = reinterpret_cast<const float4*>(cbf);
#pragma unroll
    for (int it = 0; it < 16; ++it) {
        int idx = tid + it * 256;
        int t = idx >> 6, k4 = idx & 63;
        float4 q = cf4[(size_t)midx[t] * 64 + k4];
        ushort4 zb = *reinterpret_cast<const ushort4*>(&zbuf[t * 264 + 4 * k4]);
        float zx = b2f(zb.x), zy = b2f(zb.y), zz = b2f(zb.z), zw = b2f(zb.w);
        float dx = q.x - zx, dy = q.y - zy, dz = q.z - zz, dw = q.w - zw;
        lsse += dx*dx + dy*dy + dz*dz + dw*dw;
        float4v ov = (float4v){zx + dx, zy + dy, zz + dz, zw + dw};
        __builtin_nontemporal_store(ov, &zq4[(size_t)t * 64 + k4]);
    }
    red[tid] = lsse;
    __syncthreads();
    for (int s = 128; s > 0; s >>= 1) {
        if (tid < s) red[tid] += red[tid + s];
        __syncthreads();
    }
    if (tid == 0) atomicAdd(&accg[0], red[0]);
}

// ================= fused decoder =================
// Reads per-token idx, gathers q rows (bf16, L2), d0->d1->d2 in LDS,
// vectorized x_recon stores.
__global__ __launch_bounds__(256)
void dec_fused(const int* __restrict__ idxg, const ushort* __restrict__ cbbf,
               const ushort* __restrict__ wbf,
               const float* __restrict__ bb3, const float* __restrict__ bb4,
               const float* __restrict__ bb5,
               float* __restrict__ xr)
{
    __shared__ __align__(16) ushort regA[16896];  // qbuf bf16 [64][264] -> xrbuf fp32 [64][132]
    __shared__ __align__(16) ushort regB[13312];  // h3 [64][136] @0, h4 [64][72] @8704
    __shared__ int midx[64];

    const int tid = threadIdx.x;
    const int b = blockIdx.y, s0 = blockIdx.x * 64;
    const size_t tok0 = (size_t)b * S_LEN + s0;
    const int lane = tid & 63, w = tid >> 6, r16 = lane & 15, g = lane >> 4;

    if (tid < 64) midx[tid] = idxg[tok0 + tid];
    __syncthreads();
    {   // gather q rows bf16 -> qbuf
        const int4* cb4 = reinterpret_cast<const int4*>(cbbf);
#pragma unroll
        for (int it = 0; it < 8; ++it) {
            int idx = tid + it * 256;
            int t = idx >> 5, k8 = idx & 31;
            reinterpret_cast<int4*>(regA)[t * 33 + k8] =
                cb4[(size_t)midx[t] * 32 + k8];
        }
    }
    __syncthreads();

    const ushort* wb = wbf + (size_t)b * WB_STRIDE;
    ushort* h3 = regB;
    ushort* h4 = regB + 8704;

    // d0: 256 -> 128, relu; wave cols [w*32, +32)
    {
        const ushort* wD = wb + 49152;
#pragma unroll
        for (int nt = 0; nt < 2; ++nt) {
            int col0 = w*32 + nt*16;
            float bias = bb3[col0 + r16];
            short8v bf[8];
#pragma unroll
            for (int ks = 0; ks < 8; ++ks)
                bf[ks] = *reinterpret_cast<const short8v*>(
                    wD + (size_t)(col0 + r16) * 256 + ks*32 + g*8);
#pragma unroll
            for (int tt = 0; tt < 4; ++tt) {
                float4v acc = (float4v){0.f, 0.f, 0.f, 0.f};
#pragma unroll
                for (int ks = 0; ks < 8; ++ks) {
                    short8v a = *reinterpret_cast<const short8v*>(
                        &regA[(tt*16 + r16) * 264 + ks*32 + g*8]);
                    acc = __builtin_amdgcn_mfma_f32_16x16x32_bf16(a, bf[ks], acc, 0, 0, 0);
                }
#pragma unroll
                for (int reg = 0; reg < 4; ++reg)
                    h3[(tt*16 + g*4 + reg) * 136 + col0 + r16] =
                        f2b(fmaxf(acc[reg] + bias, 0.f));
            }
        }
    }
    __syncthreads();
    // d1: 128 -> 64, relu; wave cols [w*16, +16)
    {
        const ushort* wD = wb + 81920;
        float bias = bb4[w*16 + r16];
        short8v bf[4];
#pragma unroll
        for (int ks = 0; ks < 4; ++ks)
            bf[ks] = *reinterpret_cast<const short8v*>(
                wD + (size_t)(w*16 + r16) * 128 + ks*32 + g*8);
#pragma unroll
        for (int tt = 0; tt < 4; ++tt) {
            float4v acc = (float4v){0.f, 0.f, 0.f, 0.f};
#pragma unroll
            for (int ks = 0; ks < 4; ++ks) {
                short8v a = *reinterpret_cast<const short8v*>(
                    &h3[(tt*16 + r16) * 136 + ks*32 + g*8]);
                acc = __builtin_amdgcn_mfma_f32_16x16x32_bf16(a, bf[ks], acc, 0, 0, 0);
            }
#pragma unroll
            for (int reg = 0; reg < 4; ++reg)
                h4[(tt*16 + g*4 + reg) * 72 + w*16 + r16] =
                    f2b(fmaxf(acc[reg] + bias, 0.f));
        }
    }
    __syncthreads();
    // d2: 64 -> 128, sigmoid; wave cols [w*32, +32); -> xrbuf fp32
    float* xrb = reinterpret_cast<float*>(regA);
    {
        const ushort* wD = wb + 90112;
#pragma unroll
        for (int nt = 0; nt < 2; ++nt) {
            int col0 = w*32 + nt*16;
            float bias = bb5[col0 + r16];
            short8v bf[2];
#pragma unroll
            for (int ks = 0; ks < 2; ++ks)
                bf[ks] = *reinterpret_cast<const short8v*>(
                    wD + (size_t)(col0 + r16) * 64 + ks*32 + g*8);
#pragma unroll
            for (int tt = 0; tt < 4; ++tt) {
                float4v acc = (float4v){0.f, 0.f, 0.f, 0.f};
#pragma unroll
                for (int ks = 0; ks < 2; ++ks) {
                    short8v a = *reinterpret_cast<const short8v*>(
                        &h4[(tt*16 + r16) * 72 + ks*32 + g*8]);
                    acc = __builtin_amdgcn_mfma_f32_16x16x32_bf16(a, bf[ks], acc, 0, 0, 0);
                }
#pragma unroll
                for (int reg = 0; reg < 4; ++reg) {
                    float v = acc[reg] + bias;
                    xrb[(tt*16 + g*4 + reg) * 132 + col0 + r16] =
                        1.0f / (1.0f + expf(-v));
                }
            }
        }
    }
    __syncthreads();
    {   // vectorized store (xr base only 8B-aligned -> float2)
        float2v* xr2 = reinterpret_cast<float2v*>(xr) + tok0 * 64;
#pragma unroll
        for (int it = 0; it < 16; ++it) {
            int idx = tid + it * 256;
            int t = idx >> 6, k2 = idx & 63;
            float2v ov = (float2v){xrb[t * 132 + 2*k2], xrb[t * 132 + 2*k2 + 1]};
            __builtin_nontemporal_store(ov, &xr2[(size_t)t * 64 + k2]);
        }
    }
}

// ================= finalize scalars =================
__global__ __launch_bounds__(512)
void finalize_kernel(const float* __restrict__ acc, float* __restrict__ out_scal)
{
    __shared__ float red[512];
    int tid = threadIdx.x;
    float p = acc[1 + tid] * (1.0f / (float)NTOK);
    red[tid] = p * logf(p + 1e-10f);
    __syncthreads();
    for (int s = 256; s > 0; s >>= 1) {
        if (tid < s) red[tid] += red[tid + s];
        __syncthreads();
    }
    if (tid == 0) {
        out_scal[0] = 1.25f * (acc[0] * (1.0f / 33554432.0f)); // q_latent + 0.25*e_latent
        out_scal[1] = expf(-red[0]);
    }
}

// ================= launch =================
extern "C" void kernel_launch(void* const* d_in, const int* in_sizes, int n_in,
                              void* d_out, int out_size, void* d_ws, size_t ws_size,
                              hipStream_t stream)
{
    (void)in_sizes; (void)n_in; (void)out_size; (void)ws_size;
    const float* x     = (const float*)d_in[0];
    const float* adapt = (const float*)d_in[1];
    const float* bw[6]  = {(const float*)d_in[2],  (const float*)d_in[6],  (const float*)d_in[10],
                           (const float*)d_in[14], (const float*)d_in[18], (const float*)d_in[22]};
    const float* bbp[6] = {(const float*)d_in[3],  (const float*)d_in[7],  (const float*)d_in[11],
                           (const float*)d_in[15], (const float*)d_in[19], (const float*)d_in[23]};
    const float* aw[6]  = {(const float*)d_in[4],  (const float*)d_in[8],  (const float*)d_in[12],
                           (const float*)d_in[16], (const float*)d_in[20], (const float*)d_in[24]};
    const float* ab[6]  = {(const float*)d_in[5],  (const float*)d_in[9],  (const float*)d_in[13],
                           (const float*)d_in[17], (const float*)d_in[21], (const float*)d_in[25]};
    const float* cb = (const float*)d_in[26];

    char*   wsb  = (char*)d_ws;
    ushort* wbf  = (ushort*)(wsb + WSB_W);
    ushort* cbbf = (ushort*)(wsb + WSB_CB);
    float*  cbn  = (float*) (wsb + WSB_CBN);
    float*  acc  = (float*) (wsb + WSB_ACC);
    int*    idxg = (int*)   (wsb + WSB_IDX);

    float*  out  = (float*)d_out;
    float*  zf   = out;              // z_q fp32
    float*  scal = out + OUT_SCAL;
    float*  xr   = out + OUT_XR;     // x_recon fp32

    hipMemsetAsync(acc, 0, 513 * sizeof(float), stream);

    WgenP p;
    const int loff[6]   = {0, 8192, 16384, 49152, 81920, 90112};
    const int bstart[7] = {0, 32, 64, 192, 320, 352, 384};
    for (int l = 0; l < 6; ++l) {
        p.bw[l] = bw[l]; p.aw[l] = aw[l]; p.ab[l] = ab[l]; p.loff[l] = loff[l];
    }
    for (int i = 0; i < 7; ++i) p.bstart[i] = bstart[i];

    wgen_all<<<384, 256, 0, stream>>>(p, adapt, wbf);
    cbprep_kernel<<<2, 256, 0, stream>>>(cb, cbn, cbbf);
    enc_vq<<<dim3(64, 32), 256, 0, stream>>>(x, wbf, bbp[0], bbp[1], bbp[2],
                                             cbbf, cb, cbn, zf, idxg, acc);
    dec_fused<<<dim3(64, 32), 256, 0, stream>>>(idxg, cbbf, wbf,
                                                bbp[3], bbp[4], bbp[5], xr);
    finalize_kernel<<<1, 512, 0, stream>>>(acc, scal);
}

// Round 9
// 608.461 us; speedup vs baseline: 1.2678x; 1.2678x over previous
//
#include <hip/hip_runtime.h>
#include <hip/hip_bf16.h>
#include <math.h>

#define B_N 32
#define S_LEN 4096
#define NTOK (B_N * S_LEN)   // 131072
#define EMB 256
#define NCODE 512
#define WB_STRIDE 98304      // per-batch weight entries (bf16)

typedef __attribute__((ext_vector_type(8))) short short8v;   // 8 bf16 = 4 VGPRs
typedef __attribute__((ext_vector_type(4))) float float4v;
typedef __attribute__((ext_vector_type(2))) float float2v;

__device__ inline ushort f2b(float v) {
    union { __hip_bfloat16 h; ushort u; } cv;
    cv.h = __float2bfloat16(v);   // RNE
    return cv.u;
}
__device__ inline float b2f(ushort u) {
    union { ushort u2[2]; float f; } cv;
    cv.u2[0] = 0; cv.u2[1] = u;
    return cv.f;
}

// ---- ws layout (bytes) ----
constexpr size_t WSB_W   = 0;         // ushort[3145728] generated weights (bf16)
constexpr size_t WSB_CB  = 6291456;   // ushort[131072] codebook bf16
constexpr size_t WSB_CBN = 6553600;   // float[512] codebook sq-norms
constexpr size_t WSB_ACC = 6555648;   // float[513]: [0]=sse, [1..512]=hist
constexpr size_t WSB_IDX = 6558720;   // int[131072] per-token code index

// ---- out layout (floats) ----
constexpr size_t OUT_SCAL = 33554432; // loss, perplexity
constexpr size_t OUT_XR   = 33554434; // x_recon (8B-aligned only -> float2 stores)

// ================= weight generation (all 6 layers, one launch) =================
struct WgenP {
    const float* bw[6]; const float* aw[6]; const float* ab[6];
    int loff[6]; int bstart[7];
};

__global__ __launch_bounds__(256)
void wgen_all(WgenP p, const float* __restrict__ adapt, ushort* __restrict__ wout)
{
    __shared__ float ad[B_N * 64];
    int tid = threadIdx.x;
    for (int i = tid; i < B_N * 64; i += 256) ad[i] = adapt[i];
    __syncthreads();
    int blk = blockIdx.x;
    int l = 0;
    while (l < 5 && blk >= p.bstart[l + 1]) ++l;
    int r = (blk - p.bstart[l]) * 256 + tid;

    float a[64];
    const float4* aw4 = reinterpret_cast<const float4*>(p.aw[l] + (size_t)r * 64);
#pragma unroll
    for (int q = 0; q < 16; ++q) {
        float4 v = aw4[q];
        a[4*q] = v.x; a[4*q+1] = v.y; a[4*q+2] = v.z; a[4*q+3] = v.w;
    }
    float abr = p.ab[l][r], bwr = p.bw[l][r];
    int loff = p.loff[l];
    for (int b2 = 0; b2 < B_N; ++b2) {
        const float* adp = &ad[b2 * 64];
        float s0 = 0.f, s1 = 0.f, s2 = 0.f, s3 = 0.f;
#pragma unroll
        for (int j = 0; j < 64; j += 4) {
            s0 += a[j]   * adp[j];
            s1 += a[j+1] * adp[j+1];
            s2 += a[j+2] * adp[j+2];
            s3 += a[j+3] * adp[j+3];
        }
        float s = ((s0 + s1) + (s2 + s3)) + abr;
        wout[(size_t)b2 * WB_STRIDE + loff + r] = f2b(bwr + s);
    }
}

// ================= codebook prep: norms (fp32) + bf16 copy =================
__global__ __launch_bounds__(256)
void cbprep_kernel(const float* __restrict__ cb, float* __restrict__ cbn,
                   ushort* __restrict__ cbbf)
{
    int c = blockIdx.x * 256 + threadIdx.x;
    if (c >= NCODE) return;
    const float4* c4 = reinterpret_cast<const float4*>(cb) + (size_t)c * 64;
    ushort4* o4 = reinterpret_cast<ushort4*>(cbbf) + (size_t)c * 64;
    float s = 0.f;
#pragma unroll 8
    for (int q = 0; q < 64; ++q) {
        float4 v = c4[q];
        s += v.x*v.x + v.y*v.y + v.z*v.z + v.w*v.w;
        o4[q] = make_ushort4(f2b(v.x), f2b(v.y), f2b(v.z), f2b(v.w));
    }
    cbn[c] = s;
}

// ================= fused encoder + VQ =================
// 64 tokens/block, 4 waves. Waves split output features per layer (weights
// read directly from L2). Intermediates live in LDS bf16.
// VQ: 16 chunks x 32 codes, DOUBLE-BUFFERED LDS staging with T14 async split
// (issue global loads -> compute current chunk -> ds_write next chunk).
// One barrier per chunk; stage latency hides under MFMA.
__global__ __launch_bounds__(256)
void enc_vq(const float* __restrict__ x, const ushort* __restrict__ wbf,
            const float* __restrict__ bb0, const float* __restrict__ bb1,
            const float* __restrict__ bb2,
            const ushort* __restrict__ cbbf, const float* __restrict__ cbf,
            const float* __restrict__ cbn,
            float* __restrict__ zq, int* __restrict__ idxg, float* __restrict__ accg)
{
    __shared__ __align__(16) ushort zbuf[64 * 264];   // z bf16 [64][264]
    __shared__ __align__(16) ushort regA[16896];      // xbuf[64][136] -> h1[64][136] -> 2x cbuf[32][264]
    __shared__ __align__(16) ushort regB[64 * 72];    // h0 [64][72]
    __shared__ float scbn[NCODE];
    __shared__ int   midx[64];

    const int tid = threadIdx.x;
    const int b = blockIdx.y, s0 = blockIdx.x * 64;
    const size_t tok0 = (size_t)b * S_LEN + s0;
    const int lane = tid & 63, w = tid >> 6, r16 = lane & 15, g = lane >> 4;

    for (int i = tid; i < NCODE; i += 256) scbn[i] = cbn[i];

    { // stage x fp32 -> bf16 LDS [64][136]
        const float4* x4 = reinterpret_cast<const float4*>(x) + tok0 * 32;
#pragma unroll
        for (int it = 0; it < 8; ++it) {
            int idx = tid + it * 256;
            int t = idx >> 5, k4 = idx & 31;
            float4 v = x4[(size_t)t * 32 + k4];
            *reinterpret_cast<ushort4*>(&regA[t * 136 + 4 * k4]) =
                make_ushort4(f2b(v.x), f2b(v.y), f2b(v.z), f2b(v.w));
        }
    }
    __syncthreads();

    const ushort* wb = wbf + (size_t)b * WB_STRIDE;

    // ---- e0: 128 -> 64, relu; wave owns cols [w*16, w*16+16)
    {
        const ushort* w0 = wb;                       // loff 0
        short8v bf[4];
#pragma unroll
        for (int ks = 0; ks < 4; ++ks)
            bf[ks] = *reinterpret_cast<const short8v*>(
                w0 + (size_t)(w*16 + r16) * 128 + ks*32 + g*8);
        float bias = bb0[w*16 + r16];
#pragma unroll
        for (int tt = 0; tt < 4; ++tt) {
            float4v acc = (float4v){0.f, 0.f, 0.f, 0.f};
#pragma unroll
            for (int ks = 0; ks < 4; ++ks) {
                short8v a = *reinterpret_cast<const short8v*>(
                    &regA[(tt*16 + r16) * 136 + ks*32 + g*8]);
                acc = __builtin_amdgcn_mfma_f32_16x16x32_bf16(a, bf[ks], acc, 0, 0, 0);
            }
#pragma unroll
            for (int reg = 0; reg < 4; ++reg)
                regB[(tt*16 + g*4 + reg) * 72 + w*16 + r16] =
                    f2b(fmaxf(acc[reg] + bias, 0.f));
        }
    }
    __syncthreads();

    // ---- e1: 64 -> 128, relu; wave cols [w*32, +32); h1 -> regA
    {
        const ushort* w1 = wb + 8192;
#pragma unroll
        for (int nt = 0; nt < 2; ++nt) {
            int col0 = w*32 + nt*16;
            float bias = bb1[col0 + r16];
            short8v bf[2];
#pragma unroll
            for (int ks = 0; ks < 2; ++ks)
                bf[ks] = *reinterpret_cast<const short8v*>(
                    w1 + (size_t)(col0 + r16) * 64 + ks*32 + g*8);
#pragma unroll
            for (int tt = 0; tt < 4; ++tt) {
                float4v acc = (float4v){0.f, 0.f, 0.f, 0.f};
#pragma unroll
                for (int ks = 0; ks < 2; ++ks) {
                    short8v a = *reinterpret_cast<const short8v*>(
                        &regB[(tt*16 + r16) * 72 + ks*32 + g*8]);
                    acc = __builtin_amdgcn_mfma_f32_16x16x32_bf16(a, bf[ks], acc, 0, 0, 0);
                }
#pragma unroll
                for (int reg = 0; reg < 4; ++reg)
                    regA[(tt*16 + g*4 + reg) * 136 + col0 + r16] =
                        f2b(fmaxf(acc[reg] + bias, 0.f));
            }
        }
    }
    __syncthreads();

    // ---- e2: 128 -> 256, none; wave cols [w*64, +64); z -> zbuf bf16
    {
        const ushort* w2 = wb + 16384;
#pragma unroll
        for (int nt = 0; nt < 4; ++nt) {
            int col0 = w*64 + nt*16;
            float bias = bb2[col0 + r16];
            short8v bf[4];
#pragma unroll
            for (int ks = 0; ks < 4; ++ks)
                bf[ks] = *reinterpret_cast<const short8v*>(
                    w2 + (size_t)(col0 + r16) * 128 + ks*32 + g*8);
#pragma unroll
            for (int tt = 0; tt < 4; ++tt) {
                float4v acc = (float4v){0.f, 0.f, 0.f, 0.f};
#pragma unroll
                for (int ks = 0; ks < 4; ++ks) {
                    short8v a = *reinterpret_cast<const short8v*>(
                        &regA[(tt*16 + r16) * 136 + ks*32 + g*8]);
                    acc = __builtin_amdgcn_mfma_f32_16x16x32_bf16(a, bf[ks], acc, 0, 0, 0);
                }
#pragma unroll
                for (int reg = 0; reg < 4; ++reg)
                    zbuf[(tt*16 + g*4 + reg) * 264 + col0 + r16] = f2b(acc[reg] + bias);
            }
        }
    }
    __syncthreads();   // zbuf complete; regA (h1) now free for chunk buffers

    // ---- VQ: wave owns tokens [w*16, +16); argmin over 512 codes.
    short8v az[8];
#pragma unroll
    for (int ks = 0; ks < 8; ++ks)
        az[ks] = *reinterpret_cast<const short8v*>(
            &zbuf[(w*16 + r16) * 264 + ks*32 + g*8]);

    float mv[4] = {1e30f, 1e30f, 1e30f, 1e30f};
    int   mi[4] = {0, 0, 0, 0};

    ushort* cbA = regA;            // [32][264]
    ushort* cbB = regA + 8448;     // [32][264]
    const int4* cb4 = reinterpret_cast<const int4*>(cbbf);
    const int k8 = tid & 31, cbase = tid >> 5;   // per-thread stage coords

    // prologue: stage chunk 0 into cbA (loads+writes, then barrier)
    {
        int4 stg[4];
#pragma unroll
        for (int it = 0; it < 4; ++it)
            stg[it] = cb4[(size_t)(cbase + it*8) * 32 + k8];
#pragma unroll
        for (int it = 0; it < 4; ++it)
            *reinterpret_cast<int4*>(&cbA[(cbase + it*8) * 264 + k8*8]) = stg[it];
    }
    __syncthreads();

    for (int ch = 0; ch < 16; ++ch) {
        ushort* cur = (ch & 1) ? cbB : cbA;
        ushort* nxt = (ch & 1) ? cbA : cbB;
        int4 stg[4];
        if (ch < 15) {      // T14: issue loads EARLY (drain under compute)
#pragma unroll
            for (int it = 0; it < 4; ++it)
                stg[it] = cb4[(size_t)((ch+1)*32 + cbase + it*8) * 32 + k8];
        }
        // compute current chunk: 2 tiles x 16 codes
#pragma unroll
        for (int ct = 0; ct < 2; ++ct) {
            float4v d0 = (float4v){0.f, 0.f, 0.f, 0.f};
            float4v d1 = (float4v){0.f, 0.f, 0.f, 0.f};
#pragma unroll
            for (int ks = 0; ks < 8; ks += 2) {
                short8v b0 = *reinterpret_cast<const short8v*>(
                    &cur[(ct*16 + r16) * 264 + ks*32 + g*8]);
                short8v b1 = *reinterpret_cast<const short8v*>(
                    &cur[(ct*16 + r16) * 264 + (ks+1)*32 + g*8]);
                d0 = __builtin_amdgcn_mfma_f32_16x16x32_bf16(az[ks],   b0, d0, 0, 0, 0);
                d1 = __builtin_amdgcn_mfma_f32_16x16x32_bf16(az[ks+1], b1, d1, 0, 0, 0);
            }
            int c0 = ch*32 + ct*16 + r16;   // D col = lane&15 = code
            float cn = scbn[c0];
#pragma unroll
            for (int reg = 0; reg < 4; ++reg) {
                float dd = cn - 2.0f * (d0[reg] + d1[reg]);
                if (dd < mv[reg]) { mv[reg] = dd; mi[reg] = c0; }
            }
        }
        if (ch < 15) {      // T14: write LATE (loads drained by now)
#pragma unroll
            for (int it = 0; it < 4; ++it)
                *reinterpret_cast<int4*>(&nxt[(cbase + it*8) * 264 + k8*8]) = stg[it];
        }
        __syncthreads();
    }

    // butterfly over 16 code-lanes; lex (val, idx) min == first-index argmin
#pragma unroll
    for (int m = 1; m <= 8; m <<= 1) {
#pragma unroll
        for (int reg = 0; reg < 4; ++reg) {
            float ov = __shfl_xor(mv[reg], m);
            int   oi = __shfl_xor(mi[reg], m);
            if (ov < mv[reg] || (ov == mv[reg] && oi < mi[reg])) {
                mv[reg] = ov; mi[reg] = oi;
            }
        }
    }
    if (r16 == 0) {
#pragma unroll
        for (int reg = 0; reg < 4; ++reg) midx[w*16 + g*4 + reg] = mi[reg];
    }
    __syncthreads();
    if (tid < 64) {
        idxg[tok0 + tid] = midx[tid];
        atomicAdd(&accg[1 + midx[tid]], 1.0f);
    }

    // ---- epilogue: z_q = q (== z + (q - z)); sse from bf16 zbuf.
    // Wave shuffle-reduce sse (no LDS tree, no barriers), 1 atomic/wave.
    float lsse = 0.f;
    float4v* zq4 = reinterpret_cast<float4v*>(zq) + tok0 * 64;
    const float4* cf4 = reinterpret_cast<const float4*>(cbf);
#pragma unroll
    for (int it = 0; it < 16; ++it) {
        int idx = tid + it * 256;
        int t = idx >> 6, k4 = idx & 63;
        float4 q = cf4[(size_t)midx[t] * 64 + k4];
        ushort4 zb = *reinterpret_cast<const ushort4*>(&zbuf[t * 264 + 4 * k4]);
        float dx = q.x - b2f(zb.x), dy = q.y - b2f(zb.y);
        float dz = q.z - b2f(zb.z), dw = q.w - b2f(zb.w);
        lsse += dx*dx + dy*dy + dz*dz + dw*dw;
        float4v ov = (float4v){q.x, q.y, q.z, q.w};
        __builtin_nontemporal_store(ov, &zq4[(size_t)t * 64 + k4]);
    }
#pragma unroll
    for (int m = 1; m < 64; m <<= 1) lsse += __shfl_xor(lsse, m);
    if (lane == 0) atomicAdd(&accg[0], lsse);
}

// ================= fused decoder =================
// Reads per-token idx, gathers q rows (bf16, L2), d0->d1->d2 in LDS,
// vectorized x_recon stores.
__global__ __launch_bounds__(256)
void dec_fused(const int* __restrict__ idxg, const ushort* __restrict__ cbbf,
               const ushort* __restrict__ wbf,
               const float* __restrict__ bb3, const float* __restrict__ bb4,
               const float* __restrict__ bb5,
               float* __restrict__ xr)
{
    __shared__ __align__(16) ushort regA[16896];  // qbuf bf16 [64][264] -> xrbuf fp32 [64][132]
    __shared__ __align__(16) ushort regB[13312];  // h3 [64][136] @0, h4 [64][72] @8704
    __shared__ int midx[64];

    const int tid = threadIdx.x;
    const int b = blockIdx.y, s0 = blockIdx.x * 64;
    const size_t tok0 = (size_t)b * S_LEN + s0;
    const int lane = tid & 63, w = tid >> 6, r16 = lane & 15, g = lane >> 4;

    if (tid < 64) midx[tid] = idxg[tok0 + tid];
    __syncthreads();
    {   // gather q rows bf16 -> qbuf
        const int4* cb4 = reinterpret_cast<const int4*>(cbbf);
#pragma unroll
        for (int it = 0; it < 8; ++it) {
            int idx = tid + it * 256;
            int t = idx >> 5, k8 = idx & 31;
            reinterpret_cast<int4*>(regA)[t * 33 + k8] =
                cb4[(size_t)midx[t] * 32 + k8];
        }
    }
    __syncthreads();

    const ushort* wb = wbf + (size_t)b * WB_STRIDE;
    ushort* h3 = regB;
    ushort* h4 = regB + 8704;

    // d0: 256 -> 128, relu; wave cols [w*32, +32)
    {
        const ushort* wD = wb + 49152;
#pragma unroll
        for (int nt = 0; nt < 2; ++nt) {
            int col0 = w*32 + nt*16;
            float bias = bb3[col0 + r16];
            short8v bf[8];
#pragma unroll
            for (int ks = 0; ks < 8; ++ks)
                bf[ks] = *reinterpret_cast<const short8v*>(
                    wD + (size_t)(col0 + r16) * 256 + ks*32 + g*8);
#pragma unroll
            for (int tt = 0; tt < 4; ++tt) {
                float4v acc = (float4v){0.f, 0.f, 0.f, 0.f};
#pragma unroll
                for (int ks = 0; ks < 8; ++ks) {
                    short8v a = *reinterpret_cast<const short8v*>(
                        &regA[(tt*16 + r16) * 264 + ks*32 + g*8]);
                    acc = __builtin_amdgcn_mfma_f32_16x16x32_bf16(a, bf[ks], acc, 0, 0, 0);
                }
#pragma unroll
                for (int reg = 0; reg < 4; ++reg)
                    h3[(tt*16 + g*4 + reg) * 136 + col0 + r16] =
                        f2b(fmaxf(acc[reg] + bias, 0.f));
            }
        }
    }
    __syncthreads();
    // d1: 128 -> 64, relu; wave cols [w*16, +16)
    {
        const ushort* wD = wb + 81920;
        float bias = bb4[w*16 + r16];
        short8v bf[4];
#pragma unroll
        for (int ks = 0; ks < 4; ++ks)
            bf[ks] = *reinterpret_cast<const short8v*>(
                wD + (size_t)(w*16 + r16) * 128 + ks*32 + g*8);
#pragma unroll
        for (int tt = 0; tt < 4; ++tt) {
            float4v acc = (float4v){0.f, 0.f, 0.f, 0.f};
#pragma unroll
            for (int ks = 0; ks < 4; ++ks) {
                short8v a = *reinterpret_cast<const short8v*>(
                    &h3[(tt*16 + r16) * 136 + ks*32 + g*8]);
                acc = __builtin_amdgcn_mfma_f32_16x16x32_bf16(a, bf[ks], acc, 0, 0, 0);
            }
#pragma unroll
            for (int reg = 0; reg < 4; ++reg)
                h4[(tt*16 + g*4 + reg) * 72 + w*16 + r16] =
                    f2b(fmaxf(acc[reg] + bias, 0.f));
        }
    }
    __syncthreads();
    // d2: 64 -> 128, sigmoid; wave cols [w*32, +32); -> xrbuf fp32
    float* xrb = reinterpret_cast<float*>(regA);
    {
        const ushort* wD = wb + 90112;
#pragma unroll
        for (int nt = 0; nt < 2; ++nt) {
            int col0 = w*32 + nt*16;
            float bias = bb5[col0 + r16];
            short8v bf[2];
#pragma unroll
            for (int ks = 0; ks < 2; ++ks)
                bf[ks] = *reinterpret_cast<const short8v*>(
                    wD + (size_t)(col0 + r16) * 64 + ks*32 + g*8);
#pragma unroll
            for (int tt = 0; tt < 4; ++tt) {
                float4v acc = (float4v){0.f, 0.f, 0.f, 0.f};
#pragma unroll
                for (int ks = 0; ks < 2; ++ks) {
                    short8v a = *reinterpret_cast<const short8v*>(
                        &h4[(tt*16 + r16) * 72 + ks*32 + g*8]);
                    acc = __builtin_amdgcn_mfma_f32_16x16x32_bf16(a, bf[ks], acc, 0, 0, 0);
                }
#pragma unroll
                for (int reg = 0; reg < 4; ++reg) {
                    float v = acc[reg] + bias;
                    xrb[(tt*16 + g*4 + reg) * 132 + col0 + r16] =
                        1.0f / (1.0f + expf(-v));
                }
            }
        }
    }
    __syncthreads();
    {   // vectorized store (xr base only 8B-aligned -> float2)
        float2v* xr2 = reinterpret_cast<float2v*>(xr) + tok0 * 64;
#pragma unroll
        for (int it = 0; it < 16; ++it) {
            int idx = tid + it * 256;
            int t = idx >> 6, k2 = idx & 63;
            float2v ov = (float2v){xrb[t * 132 + 2*k2], xrb[t * 132 + 2*k2 + 1]};
            __builtin_nontemporal_store(ov, &xr2[(size_t)t * 64 + k2]);
        }
    }
}

// ================= finalize scalars =================
__global__ __launch_bounds__(512)
void finalize_kernel(const float* __restrict__ acc, float* __restrict__ out_scal)
{
    __shared__ float red[512];
    int tid = threadIdx.x;
    float p = acc[1 + tid] * (1.0f / (float)NTOK);
    red[tid] = p * logf(p + 1e-10f);
    __syncthreads();
    for (int s = 256; s > 0; s >>= 1) {
        if (tid < s) red[tid] += red[tid + s];
        __syncthreads();
    }
    if (tid == 0) {
        out_scal[0] = 1.25f * (acc[0] * (1.0f / 33554432.0f)); // q_latent + 0.25*e_latent
        out_scal[1] = expf(-red[0]);
    }
}

// ================= launch =================
extern "C" void kernel_launch(void* const* d_in, const int* in_sizes, int n_in,
                              void* d_out, int out_size, void* d_ws, size_t ws_size,
                              hipStream_t stream)
{
    (void)in_sizes; (void)n_in; (void)out_size; (void)ws_size;
    const float* x     = (const float*)d_in[0];
    const float* adapt = (const float*)d_in[1];
    const float* bw[6]  = {(const float*)d_in[2],  (const float*)d_in[6],  (const float*)d_in[10],
                           (const float*)d_in[14], (const float*)d_in[18], (const float*)d_in[22]};
    const float* bbp[6] = {(const float*)d_in[3],  (const float*)d_in[7],  (const float*)d_in[11],
                           (const float*)d_in[15], (const float*)d_in[19], (const float*)d_in[23]};
    const float* aw[6]  = {(const float*)d_in[4],  (const float*)d_in[8],  (const float*)d_in[12],
                           (const float*)d_in[16], (const float*)d_in[20], (const float*)d_in[24]};
    const float* ab[6]  = {(const float*)d_in[5],  (const float*)d_in[9],  (const float*)d_in[13],
                           (const float*)d_in[17], (const float*)d_in[21], (const float*)d_in[25]};
    const float* cb = (const float*)d_in[26];

    char*   wsb  = (char*)d_ws;
    ushort* wbf  = (ushort*)(wsb + WSB_W);
    ushort* cbbf = (ushort*)(wsb + WSB_CB);
    float*  cbn  = (float*) (wsb + WSB_CBN);
    float*  acc  = (float*) (wsb + WSB_ACC);
    int*    idxg = (int*)   (wsb + WSB_IDX);

    float*  out  = (float*)d_out;
    float*  zf   = out;              // z_q fp32
    float*  scal = out + OUT_SCAL;
    float*  xr   = out + OUT_XR;     // x_recon fp32

    hipMemsetAsync(acc, 0, 513 * sizeof(float), stream);

    WgenP p;
    const int loff[6]   = {0, 8192, 16384, 49152, 81920, 90112};
    const int bstart[7] = {0, 32, 64, 192, 320, 352, 384};
    for (int l = 0; l < 6; ++l) {
        p.bw[l] = bw[l]; p.aw[l] = aw[l]; p.ab[l] = ab[l]; p.loff[l] = loff[l];
    }
    for (int i = 0; i < 7; ++i) p.bstart[i] = bstart[i];

    wgen_all<<<384, 256, 0, stream>>>(p, adapt, wbf);
    cbprep_kernel<<<2, 256, 0, stream>>>(cb, cbn, cbbf);
    enc_vq<<<dim3(64, 32), 256, 0, stream>>>(x, wbf, bbp[0], bbp[1], bbp[2],
                                             cbbf, cb, cbn, zf, idxg, acc);
    dec_fused<<<dim3(64, 32), 256, 0, stream>>>(idxg, cbbf, wbf,
                                                bbp[3], bbp[4], bbp[5], xr);
    finalize_kernel<<<1, 512, 0, stream>>>(acc, scal);
}

// Round 10
// 597.845 us; speedup vs baseline: 1.2903x; 1.0178x over previous
//
#include <hip/hip_runtime.h>
#include <hip/hip_bf16.h>
#include <math.h>

#define B_N 32
#define S_LEN 4096
#define NTOK (B_N * S_LEN)   // 131072
#define EMB 256
#define NCODE 512
#define WB_STRIDE 98304      // per-batch weight entries (bf16)

typedef __attribute__((ext_vector_type(8))) short short8v;   // 8 bf16 = 4 VGPRs
typedef __attribute__((ext_vector_type(4))) float float4v;
typedef __attribute__((ext_vector_type(2))) float float2v;

__device__ inline ushort f2b(float v) {
    union { __hip_bfloat16 h; ushort u; } cv;
    cv.h = __float2bfloat16(v);   // RNE
    return cv.u;
}
__device__ inline float b2f(ushort u) {
    union { ushort u2[2]; float f; } cv;
    cv.u2[0] = 0; cv.u2[1] = u;
    return cv.f;
}

// ---- ws layout (bytes) ----
constexpr size_t WSB_W   = 0;         // ushort[3145728] generated weights (bf16)
constexpr size_t WSB_CB  = 6291456;   // ushort[131072] codebook bf16
constexpr size_t WSB_CBN = 6553600;   // float[512] codebook sq-norms
constexpr size_t WSB_ACC = 6555648;   // float[513]: [0]=sse, [1..512]=hist
constexpr size_t WSB_IDX = 6558720;   // int[131072] per-token code index

// ---- out layout (floats) ----
constexpr size_t OUT_SCAL = 33554432; // loss, perplexity
constexpr size_t OUT_XR   = 33554434; // x_recon (8B-aligned only -> float2 stores)

// ================= weight generation (all 6 layers, one launch) =================
struct WgenP {
    const float* bw[6]; const float* aw[6]; const float* ab[6];
    int loff[6]; int bstart[7];
};

__global__ __launch_bounds__(256)
void wgen_all(WgenP p, const float* __restrict__ adapt, ushort* __restrict__ wout)
{
    __shared__ float ad[B_N * 64];
    int tid = threadIdx.x;
    for (int i = tid; i < B_N * 64; i += 256) ad[i] = adapt[i];
    __syncthreads();
    int blk = blockIdx.x;
    int l = 0;
    while (l < 5 && blk >= p.bstart[l + 1]) ++l;
    int r = (blk - p.bstart[l]) * 256 + tid;

    float a[64];
    const float4* aw4 = reinterpret_cast<const float4*>(p.aw[l] + (size_t)r * 64);
#pragma unroll
    for (int q = 0; q < 16; ++q) {
        float4 v = aw4[q];
        a[4*q] = v.x; a[4*q+1] = v.y; a[4*q+2] = v.z; a[4*q+3] = v.w;
    }
    float abr = p.ab[l][r], bwr = p.bw[l][r];
    int loff = p.loff[l];
    for (int b2 = 0; b2 < B_N; ++b2) {
        const float* adp = &ad[b2 * 64];
        float s0 = 0.f, s1 = 0.f, s2 = 0.f, s3 = 0.f;
#pragma unroll
        for (int j = 0; j < 64; j += 4) {
            s0 += a[j]   * adp[j];
            s1 += a[j+1] * adp[j+1];
            s2 += a[j+2] * adp[j+2];
            s3 += a[j+3] * adp[j+3];
        }
        float s = ((s0 + s1) + (s2 + s3)) + abr;
        wout[(size_t)b2 * WB_STRIDE + loff + r] = f2b(bwr + s);
    }
}

// ================= codebook prep: norms (fp32) + bf16 copy =================
__global__ __launch_bounds__(256)
void cbprep_kernel(const float* __restrict__ cb, float* __restrict__ cbn,
                   ushort* __restrict__ cbbf)
{
    int c = blockIdx.x * 256 + threadIdx.x;
    if (c >= NCODE) return;
    const float4* c4 = reinterpret_cast<const float4*>(cb) + (size_t)c * 64;
    ushort4* o4 = reinterpret_cast<ushort4*>(cbbf) + (size_t)c * 64;
    float s = 0.f;
#pragma unroll 8
    for (int q = 0; q < 64; ++q) {
        float4 v = c4[q];
        s += v.x*v.x + v.y*v.y + v.z*v.z + v.w*v.w;
        o4[q] = make_ushort4(f2b(v.x), f2b(v.y), f2b(v.z), f2b(v.w));
    }
    cbn[c] = s;
}

// ================= fused encoder + VQ =================
// 64 tokens/block, 4 waves.  LDS SHRUNK to ~36.6 KB -> 4 blocks/CU (was 2):
//  - zbuf eliminated: sse = ||z||^2 + mv_min (argmin distance), znorm from az regs
//  - e2 runs in two 32-token halves through a [32][264] exchange buffer
//  - one union buffer XB serves x/h1 + h0 + z-exchange + VQ double-buffer
// VQ: 16 chunks x 32 codes, double-buffered with T14 async split (as R9).
__global__ __launch_bounds__(256, 4)
void enc_vq(const float* __restrict__ x, const ushort* __restrict__ wbf,
            const float* __restrict__ bb0, const float* __restrict__ bb1,
            const float* __restrict__ bb2,
            const ushort* __restrict__ cbbf, const float* __restrict__ cbf,
            const float* __restrict__ cbn,
            float* __restrict__ zq, int* __restrict__ idxg, float* __restrict__ accg)
{
    // XB union (ushort units):
    //   [0,8704)       x-buf / h1   [64][136]
    //   [8704,13312)   h0           [64][72]     (dead after e1)
    //   [8704,17152)   z-exchange   [32][264]    (e2 halves)
    //   [0,8448)+[8448,16896)  VQ cbufA/cbufB [32][264] each (after az loaded)
    __shared__ __align__(16) ushort XB[17152];
    __shared__ float scbn[NCODE];
    __shared__ int   midx[64];

    const int tid = threadIdx.x;
    const int b = blockIdx.y, s0 = blockIdx.x * 64;
    const size_t tok0 = (size_t)b * S_LEN + s0;
    const int lane = tid & 63, w = tid >> 6, r16 = lane & 15, g = lane >> 4;

    ushort* xh1 = XB;            // stride 136
    ushort* h0  = XB + 8704;     // stride 72
    ushort* zx  = XB + 8704;     // stride 264 (32 rows)

    for (int i = tid; i < NCODE; i += 256) scbn[i] = cbn[i];

    { // stage x fp32 -> bf16 LDS [64][136]
        const float4* x4 = reinterpret_cast<const float4*>(x) + tok0 * 32;
#pragma unroll
        for (int it = 0; it < 8; ++it) {
            int idx = tid + it * 256;
            int t = idx >> 5, k4 = idx & 31;
            float4 v = x4[(size_t)t * 32 + k4];
            *reinterpret_cast<ushort4*>(&xh1[t * 136 + 4 * k4]) =
                make_ushort4(f2b(v.x), f2b(v.y), f2b(v.z), f2b(v.w));
        }
    }
    __syncthreads();

    const ushort* wb = wbf + (size_t)b * WB_STRIDE;

    // ---- e0: 128 -> 64, relu; wave owns cols [w*16, w*16+16)
    {
        const ushort* w0 = wb;                       // loff 0
        short8v bf[4];
#pragma unroll
        for (int ks = 0; ks < 4; ++ks)
            bf[ks] = *reinterpret_cast<const short8v*>(
                w0 + (size_t)(w*16 + r16) * 128 + ks*32 + g*8);
        float bias = bb0[w*16 + r16];
#pragma unroll
        for (int tt = 0; tt < 4; ++tt) {
            float4v acc = (float4v){0.f, 0.f, 0.f, 0.f};
#pragma unroll
            for (int ks = 0; ks < 4; ++ks) {
                short8v a = *reinterpret_cast<const short8v*>(
                    &xh1[(tt*16 + r16) * 136 + ks*32 + g*8]);
                acc = __builtin_amdgcn_mfma_f32_16x16x32_bf16(a, bf[ks], acc, 0, 0, 0);
            }
#pragma unroll
            for (int reg = 0; reg < 4; ++reg)
                h0[(tt*16 + g*4 + reg) * 72 + w*16 + r16] =
                    f2b(fmaxf(acc[reg] + bias, 0.f));
        }
    }
    __syncthreads();

    // ---- e1: 64 -> 128, relu; wave cols [w*32, +32); h1 -> xh1
    {
        const ushort* w1 = wb + 8192;
#pragma unroll
        for (int nt = 0; nt < 2; ++nt) {
            int col0 = w*32 + nt*16;
            float bias = bb1[col0 + r16];
            short8v bf[2];
#pragma unroll
            for (int ks = 0; ks < 2; ++ks)
                bf[ks] = *reinterpret_cast<const short8v*>(
                    w1 + (size_t)(col0 + r16) * 64 + ks*32 + g*8);
#pragma unroll
            for (int tt = 0; tt < 4; ++tt) {
                float4v acc = (float4v){0.f, 0.f, 0.f, 0.f};
#pragma unroll
                for (int ks = 0; ks < 2; ++ks) {
                    short8v a = *reinterpret_cast<const short8v*>(
                        &h0[(tt*16 + r16) * 72 + ks*32 + g*8]);
                    acc = __builtin_amdgcn_mfma_f32_16x16x32_bf16(a, bf[ks], acc, 0, 0, 0);
                }
#pragma unroll
                for (int reg = 0; reg < 4; ++reg)
                    xh1[(tt*16 + g*4 + reg) * 136 + col0 + r16] =
                        f2b(fmaxf(acc[reg] + bias, 0.f));
            }
        }
    }
    __syncthreads();

    // ---- e2: 128 -> 256 in TWO 32-token halves via zx; az loaded per half
    const ushort* w2 = wb + 16384;
    short8v az[8];
#pragma unroll
    for (int half = 0; half < 2; ++half) {
#pragma unroll
        for (int nt = 0; nt < 4; ++nt) {
            int col0 = w*64 + nt*16;
            float bias = bb2[col0 + r16];
            short8v bf[4];
#pragma unroll
            for (int ks = 0; ks < 4; ++ks)
                bf[ks] = *reinterpret_cast<const short8v*>(
                    w2 + (size_t)(col0 + r16) * 128 + ks*32 + g*8);
#pragma unroll
            for (int tt2 = 0; tt2 < 2; ++tt2) {
                int tt = half*2 + tt2;
                float4v acc = (float4v){0.f, 0.f, 0.f, 0.f};
#pragma unroll
                for (int ks = 0; ks < 4; ++ks) {
                    short8v a = *reinterpret_cast<const short8v*>(
                        &xh1[(tt*16 + r16) * 136 + ks*32 + g*8]);
                    acc = __builtin_amdgcn_mfma_f32_16x16x32_bf16(a, bf[ks], acc, 0, 0, 0);
                }
#pragma unroll
                for (int reg = 0; reg < 4; ++reg)
                    zx[(tt2*16 + g*4 + reg) * 264 + col0 + r16] = f2b(acc[reg] + bias);
            }
        }
        __syncthreads();
        if ((w >> 1) == half) {   // waves owning tokens of this half load az
            int lrow = (w & 1)*16 + r16;
#pragma unroll
            for (int ks = 0; ks < 8; ++ks)
                az[ks] = *reinterpret_cast<const short8v*>(
                    &zx[lrow * 264 + ks*32 + g*8]);
        }
        __syncthreads();
    }

    // znorm per token (from az regs): sum az^2 per lane, reduce across g-lanes
    float znorm = 0.f;
#pragma unroll
    for (int ks = 0; ks < 8; ++ks)
#pragma unroll
        for (int j = 0; j < 8; ++j) {
            float zv = b2f((ushort)az[ks][j]);
            znorm += zv * zv;
        }
    znorm += __shfl_xor(znorm, 16);
    znorm += __shfl_xor(znorm, 32);   // ||z_{w*16+r16}||^2, replicated over g

    // ---- VQ: wave owns tokens [w*16, +16); argmin over 512 codes.
    float mv[4] = {1e30f, 1e30f, 1e30f, 1e30f};
    int   mi[4] = {0, 0, 0, 0};

    ushort* cbA = XB;              // [32][264]
    ushort* cbB = XB + 8448;       // [32][264]
    const int4* cb4 = reinterpret_cast<const int4*>(cbbf);
    const int k8 = tid & 31, cbase = tid >> 5;   // per-thread stage coords

    // prologue: stage chunk 0 into cbA
    {
        int4 stg[4];
#pragma unroll
        for (int it = 0; it < 4; ++it)
            stg[it] = cb4[(size_t)(cbase + it*8) * 32 + k8];
#pragma unroll
        for (int it = 0; it < 4; ++it)
            *reinterpret_cast<int4*>(&cbA[(cbase + it*8) * 264 + k8*8]) = stg[it];
    }
    __syncthreads();

    for (int ch = 0; ch < 16; ++ch) {
        ushort* cur = (ch & 1) ? cbB : cbA;
        ushort* nxt = (ch & 1) ? cbA : cbB;
        int4 stg[4];
        if (ch < 15) {      // T14: issue loads EARLY (drain under compute)
#pragma unroll
            for (int it = 0; it < 4; ++it)
                stg[it] = cb4[(size_t)((ch+1)*32 + cbase + it*8) * 32 + k8];
        }
#pragma unroll
        for (int ct = 0; ct < 2; ++ct) {
            float4v d0 = (float4v){0.f, 0.f, 0.f, 0.f};
            float4v d1 = (float4v){0.f, 0.f, 0.f, 0.f};
#pragma unroll
            for (int ks = 0; ks < 8; ks += 2) {
                short8v b0 = *reinterpret_cast<const short8v*>(
                    &cur[(ct*16 + r16) * 264 + ks*32 + g*8]);
                short8v b1 = *reinterpret_cast<const short8v*>(
                    &cur[(ct*16 + r16) * 264 + (ks+1)*32 + g*8]);
                d0 = __builtin_amdgcn_mfma_f32_16x16x32_bf16(az[ks],   b0, d0, 0, 0, 0);
                d1 = __builtin_amdgcn_mfma_f32_16x16x32_bf16(az[ks+1], b1, d1, 0, 0, 0);
            }
            int c0 = ch*32 + ct*16 + r16;   // D col = lane&15 = code
            float cn = scbn[c0];
#pragma unroll
            for (int reg = 0; reg < 4; ++reg) {
                float dd = cn - 2.0f * (d0[reg] + d1[reg]);
                if (dd < mv[reg]) { mv[reg] = dd; mi[reg] = c0; }
            }
        }
        if (ch < 15) {      // T14: write LATE
#pragma unroll
            for (int it = 0; it < 4; ++it)
                *reinterpret_cast<int4*>(&nxt[(cbase + it*8) * 264 + k8*8]) = stg[it];
        }
        __syncthreads();
    }

    // butterfly over 16 code-lanes; lex (val, idx) min == first-index argmin
#pragma unroll
    for (int m = 1; m <= 8; m <<= 1) {
#pragma unroll
        for (int reg = 0; reg < 4; ++reg) {
            float ov = __shfl_xor(mv[reg], m);
            int   oi = __shfl_xor(mi[reg], m);
            if (ov < mv[reg] || (ov == mv[reg] && oi < mi[reg])) {
                mv[reg] = ov; mi[reg] = oi;
            }
        }
    }
    if (r16 == 0) {
#pragma unroll
        for (int reg = 0; reg < 4; ++reg) midx[w*16 + g*4 + reg] = mi[reg];
    }
    __syncthreads();
    if (tid < 64) {
        idxg[tok0 + tid] = midx[tid];
        atomicAdd(&accg[1 + midx[tid]], 1.0f);
    }

    // ---- sse = sum_tokens (||z||^2 + mv_min); one lane per token contributes
    float contrib = 0.f;
#pragma unroll
    for (int reg = 0; reg < 4; ++reg)
        if (r16 == g*4 + reg) contrib = znorm + mv[reg];
#pragma unroll
    for (int m = 1; m < 64; m <<= 1) contrib += __shfl_xor(contrib, m);
    if (lane == 0) atomicAdd(&accg[0], contrib);

    // ---- z_q = q (fp32 codebook gather), NT streamed
    float4v* zq4 = reinterpret_cast<float4v*>(zq) + tok0 * 64;
    const float4* cf4 = reinterpret_cast<const float4*>(cbf);
#pragma unroll
    for (int it = 0; it < 16; ++it) {
        int idx = tid + it * 256;
        int t = idx >> 6, k4 = idx & 63;
        float4 q = cf4[(size_t)midx[t] * 64 + k4];
        float4v ov = (float4v){q.x, q.y, q.z, q.w};
        __builtin_nontemporal_store(ov, &zq4[(size_t)t * 64 + k4]);
    }
}

// ================= fused decoder =================
// Reads per-token idx, gathers q rows (bf16, L2), d0->d1->d2 in LDS,
// vectorized x_recon stores.
__global__ __launch_bounds__(256)
void dec_fused(const int* __restrict__ idxg, const ushort* __restrict__ cbbf,
               const ushort* __restrict__ wbf,
               const float* __restrict__ bb3, const float* __restrict__ bb4,
               const float* __restrict__ bb5,
               float* __restrict__ xr)
{
    __shared__ __align__(16) ushort regA[16896];  // qbuf bf16 [64][264] -> xrbuf fp32 [64][132]
    __shared__ __align__(16) ushort regB[13312];  // h3 [64][136] @0, h4 [64][72] @8704
    __shared__ int midx[64];

    const int tid = threadIdx.x;
    const int b = blockIdx.y, s0 = blockIdx.x * 64;
    const size_t tok0 = (size_t)b * S_LEN + s0;
    const int lane = tid & 63, w = tid >> 6, r16 = lane & 15, g = lane >> 4;

    if (tid < 64) midx[tid] = idxg[tok0 + tid];
    __syncthreads();
    {   // gather q rows bf16 -> qbuf
        const int4* cb4 = reinterpret_cast<const int4*>(cbbf);
#pragma unroll
        for (int it = 0; it < 8; ++it) {
            int idx = tid + it * 256;
            int t = idx >> 5, k8 = idx & 31;
            reinterpret_cast<int4*>(regA)[t * 33 + k8] =
                cb4[(size_t)midx[t] * 32 + k8];
        }
    }
    __syncthreads();

    const ushort* wb = wbf + (size_t)b * WB_STRIDE;
    ushort* h3 = regB;
    ushort* h4 = regB + 8704;

    // d0: 256 -> 128, relu; wave cols [w*32, +32)
    {
        const ushort* wD = wb + 49152;
#pragma unroll
        for (int nt = 0; nt < 2; ++nt) {
            int col0 = w*32 + nt*16;
            float bias = bb3[col0 + r16];
            short8v bf[8];
#pragma unroll
            for (int ks = 0; ks < 8; ++ks)
                bf[ks] = *reinterpret_cast<const short8v*>(
                    wD + (size_t)(col0 + r16) * 256 + ks*32 + g*8);
#pragma unroll
            for (int tt = 0; tt < 4; ++tt) {
                float4v acc = (float4v){0.f, 0.f, 0.f, 0.f};
#pragma unroll
                for (int ks = 0; ks < 8; ++ks) {
                    short8v a = *reinterpret_cast<const short8v*>(
                        &regA[(tt*16 + r16) * 264 + ks*32 + g*8]);
                    acc = __builtin_amdgcn_mfma_f32_16x16x32_bf16(a, bf[ks], acc, 0, 0, 0);
                }
#pragma unroll
                for (int reg = 0; reg < 4; ++reg)
                    h3[(tt*16 + g*4 + reg) * 136 + col0 + r16] =
                        f2b(fmaxf(acc[reg] + bias, 0.f));
            }
        }
    }
    __syncthreads();
    // d1: 128 -> 64, relu; wave cols [w*16, +16)
    {
        const ushort* wD = wb + 81920;
        float bias = bb4[w*16 + r16];
        short8v bf[4];
#pragma unroll
        for (int ks = 0; ks < 4; ++ks)
            bf[ks] = *reinterpret_cast<const short8v*>(
                wD + (size_t)(w*16 + r16) * 128 + ks*32 + g*8);
#pragma unroll
        for (int tt = 0; tt < 4; ++tt) {
            float4v acc = (float4v){0.f, 0.f, 0.f, 0.f};
#pragma unroll
            for (int ks = 0; ks < 4; ++ks) {
                short8v a = *reinterpret_cast<const short8v*>(
                    &h3[(tt*16 + r16) * 136 + ks*32 + g*8]);
                acc = __builtin_amdgcn_mfma_f32_16x16x32_bf16(a, bf[ks], acc, 0, 0, 0);
            }
#pragma unroll
            for (int reg = 0; reg < 4; ++reg)
                h4[(tt*16 + g*4 + reg) * 72 + w*16 + r16] =
                    f2b(fmaxf(acc[reg] + bias, 0.f));
        }
    }
    __syncthreads();
    // d2: 64 -> 128, sigmoid; wave cols [w*32, +32); -> xrbuf fp32
    float* xrb = reinterpret_cast<float*>(regA);
    {
        const ushort* wD = wb + 90112;
#pragma unroll
        for (int nt = 0; nt < 2; ++nt) {
            int col0 = w*32 + nt*16;
            float bias = bb5[col0 + r16];
            short8v bf[2];
#pragma unroll
            for (int ks = 0; ks < 2; ++ks)
                bf[ks] = *reinterpret_cast<const short8v*>(
                    wD + (size_t)(col0 + r16) * 64 + ks*32 + g*8);
#pragma unroll
            for (int tt = 0; tt < 4; ++tt) {
                float4v acc = (float4v){0.f, 0.f, 0.f, 0.f};
#pragma unroll
                for (int ks = 0; ks < 2; ++ks) {
                    short8v a = *reinterpret_cast<const short8v*>(
                        &h4[(tt*16 + r16) * 72 + ks*32 + g*8]);
                    acc = __builtin_amdgcn_mfma_f32_16x16x32_bf16(a, bf[ks], acc, 0, 0, 0);
                }
#pragma unroll
                for (int reg = 0; reg < 4; ++reg) {
                    float v = acc[reg] + bias;
                    xrb[(tt*16 + g*4 + reg) * 132 + col0 + r16] =
                        1.0f / (1.0f + expf(-v));
                }
            }
        }
    }
    __syncthreads();
    {   // vectorized store (xr base only 8B-aligned -> float2)
        float2v* xr2 = reinterpret_cast<float2v*>(xr) + tok0 * 64;
#pragma unroll
        for (int it = 0; it < 16; ++it) {
            int idx = tid + it * 256;
            int t = idx >> 6, k2 = idx & 63;
            float2v ov = (float2v){xrb[t * 132 + 2*k2], xrb[t * 132 + 2*k2 + 1]};
            __builtin_nontemporal_store(ov, &xr2[(size_t)t * 64 + k2]);
        }
    }
}

// ================= finalize scalars =================
__global__ __launch_bounds__(512)
void finalize_kernel(const float* __restrict__ acc, float* __restrict__ out_scal)
{
    __shared__ float red[512];
    int tid = threadIdx.x;
    float p = acc[1 + tid] * (1.0f / (float)NTOK);
    red[tid] = p * logf(p + 1e-10f);
    __syncthreads();
    for (int s = 256; s > 0; s >>= 1) {
        if (tid < s) red[tid] += red[tid + s];
        __syncthreads();
    }
    if (tid == 0) {
        out_scal[0] = 1.25f * (acc[0] * (1.0f / 33554432.0f)); // q_latent + 0.25*e_latent
        out_scal[1] = expf(-red[0]);
    }
}

// ================= launch =================
extern "C" void kernel_launch(void* const* d_in, const int* in_sizes, int n_in,
                              void* d_out, int out_size, void* d_ws, size_t ws_size,
                              hipStream_t stream)
{
    (void)in_sizes; (void)n_in; (void)out_size; (void)ws_size;
    const float* x     = (const float*)d_in[0];
    const float* adapt = (const float*)d_in[1];
    const float* bw[6]  = {(const float*)d_in[2],  (const float*)d_in[6],  (const float*)d_in[10],
                           (const float*)d_in[14], (const float*)d_in[18], (const float*)d_in[22]};
    const float* bbp[6] = {(const float*)d_in[3],  (const float*)d_in[7],  (const float*)d_in[11],
                           (const float*)d_in[15], (const float*)d_in[19], (const float*)d_in[23]};
    const float* aw[6]  = {(const float*)d_in[4],  (const float*)d_in[8],  (const float*)d_in[12],
                           (const float*)d_in[16], (const float*)d_in[20], (const float*)d_in[24]};
    const float* ab[6]  = {(const float*)d_in[5],  (const float*)d_in[9],  (const float*)d_in[13],
                           (const float*)d_in[17], (const float*)d_in[21], (const float*)d_in[25]};
    const float* cb = (const float*)d_in[26];

    char*   wsb  = (char*)d_ws;
    ushort* wbf  = (ushort*)(wsb + WSB_W);
    ushort* cbbf = (ushort*)(wsb + WSB_CB);
    float*  cbn  = (float*) (wsb + WSB_CBN);
    float*  acc  = (float*) (wsb + WSB_ACC);
    int*    idxg = (int*)   (wsb + WSB_IDX);

    float*  out  = (float*)d_out;
    float*  zf   = out;              // z_q fp32
    float*  scal = out + OUT_SCAL;
    float*  xr   = out + OUT_XR;     // x_recon fp32

    hipMemsetAsync(acc, 0, 513 * sizeof(float), stream);

    WgenP p;
    const int loff[6]   = {0, 8192, 16384, 49152, 81920, 90112};
    const int bstart[7] = {0, 32, 64, 192, 320, 352, 384};
    for (int l = 0; l < 6; ++l) {
        p.bw[l] = bw[l]; p.aw[l] = aw[l]; p.ab[l] = ab[l]; p.loff[l] = loff[l];
    }
    for (int i = 0; i < 7; ++i) p.bstart[i] = bstart[i];

    wgen_all<<<384, 256, 0, stream>>>(p, adapt, wbf);
    cbprep_kernel<<<2, 256, 0, stream>>>(cb, cbn, cbbf);
    enc_vq<<<dim3(64, 32), 256, 0, stream>>>(x, wbf, bbp[0], bbp[1], bbp[2],
                                             cbbf, cb, cbn, zf, idxg, acc);
    dec_fused<<<dim3(64, 32), 256, 0, stream>>>(idxg, cbbf, wbf,
                                                bbp[3], bbp[4], bbp[5], xr);
    finalize_kernel<<<1, 512, 0, stream>>>(acc, scal);
}

// Round 13
// 573.813 us; speedup vs baseline: 1.3444x; 1.0419x over previous
//
#include <hip/hip_runtime.h>
#include <hip/hip_bf16.h>
#include <math.h>

#define B_N 32
#define S_LEN 4096
#define NTOK (B_N * S_LEN)   // 131072
#define EMB 256
#define NCODE 512
#define WB_STRIDE 98304      // per-batch weight entries (bf16)

typedef __attribute__((ext_vector_type(8))) short short8v;   // 8 bf16 = 4 VGPRs
typedef __attribute__((ext_vector_type(4))) float float4v;
typedef __attribute__((ext_vector_type(2))) float float2v;

__device__ inline ushort f2b(float v) {
    union { __hip_bfloat16 h; ushort u; } cv;
    cv.h = __float2bfloat16(v);   // RNE
    return cv.u;
}
__device__ inline float b2f(ushort u) {
    union { ushort u2[2]; float f; } cv;
    cv.u2[0] = 0; cv.u2[1] = u;
    return cv.f;
}

// ---- ws layout (bytes) ----
constexpr size_t WSB_W   = 0;         // ushort[3145728] generated weights (bf16)
constexpr size_t WSB_CB  = 6291456;   // ushort[131072] codebook bf16
constexpr size_t WSB_CBN = 6553600;   // float[512] codebook sq-norms
constexpr size_t WSB_ACC = 6555648;   // float[513]: [0]=sse, [1..512]=hist

// ---- out layout (floats) ----
constexpr size_t OUT_SCAL = 33554432; // loss, perplexity
constexpr size_t OUT_XR   = 33554434; // x_recon (8B-aligned only -> float2 stores)

// ================= weight generation (all 6 layers, one launch) =================
struct WgenP {
    const float* bw[6]; const float* aw[6]; const float* ab[6];
    int loff[6]; int bstart[7];
};

__global__ __launch_bounds__(256)
void wgen_all(WgenP p, const float* __restrict__ adapt, ushort* __restrict__ wout)
{
    __shared__ float ad[B_N * 64];
    int tid = threadIdx.x;
    for (int i = tid; i < B_N * 64; i += 256) ad[i] = adapt[i];
    __syncthreads();
    int blk = blockIdx.x;
    int l = 0;
    while (l < 5 && blk >= p.bstart[l + 1]) ++l;
    int r = (blk - p.bstart[l]) * 256 + tid;

    float a[64];
    const float4* aw4 = reinterpret_cast<const float4*>(p.aw[l] + (size_t)r * 64);
#pragma unroll
    for (int q = 0; q < 16; ++q) {
        float4 v = aw4[q];
        a[4*q] = v.x; a[4*q+1] = v.y; a[4*q+2] = v.z; a[4*q+3] = v.w;
    }
    float abr = p.ab[l][r], bwr = p.bw[l][r];
    int loff = p.loff[l];
    for (int b2 = 0; b2 < B_N; ++b2) {
        const float* adp = &ad[b2 * 64];
        float s0 = 0.f, s1 = 0.f, s2 = 0.f, s3 = 0.f;
#pragma unroll
        for (int j = 0; j < 64; j += 4) {
            s0 += a[j]   * adp[j];
            s1 += a[j+1] * adp[j+1];
            s2 += a[j+2] * adp[j+2];
            s3 += a[j+3] * adp[j+3];
        }
        float s = ((s0 + s1) + (s2 + s3)) + abr;
        wout[(size_t)b2 * WB_STRIDE + loff + r] = f2b(bwr + s);
    }
}

// ================= codebook prep: norms (fp32) + bf16 copy =================
__global__ __launch_bounds__(256)
void cbprep_kernel(const float* __restrict__ cb, float* __restrict__ cbn,
                   ushort* __restrict__ cbbf)
{
    int c = blockIdx.x * 256 + threadIdx.x;
    if (c >= NCODE) return;
    const float4* c4 = reinterpret_cast<const float4*>(cb) + (size_t)c * 64;
    ushort4* o4 = reinterpret_cast<ushort4*>(cbbf) + (size_t)c * 64;
    float s = 0.f;
#pragma unroll 8
    for (int q = 0; q < 64; ++q) {
        float4 v = c4[q];
        s += v.x*v.x + v.y*v.y + v.z*v.z + v.w*v.w;
        o4[q] = make_ushort4(f2b(v.x), f2b(v.y), f2b(v.z), f2b(v.w));
    }
    cbn[c] = s;
}

// ================= FUSED encoder + VQ + decoder =================
// 64 tokens/block, 4 waves. Enc part = R10 verbatim; after VQ the block's
// midx feeds the decoder in the SAME kernel (idxg round-trip eliminated).
// One LDS pool (~51 KB) re-laid per phase; 2 blocks/CU.
__global__ __launch_bounds__(256, 2)
void encdec_vq(const float* __restrict__ x, const ushort* __restrict__ wbf,
               const float* __restrict__ bb0, const float* __restrict__ bb1,
               const float* __restrict__ bb2, const float* __restrict__ bb3,
               const float* __restrict__ bb4, const float* __restrict__ bb5,
               const ushort* __restrict__ cbbf, const float* __restrict__ cbf,
               const float* __restrict__ cbn,
               float* __restrict__ zq, float* __restrict__ xr,
               float* __restrict__ accg)
{
    // POOL layout (ushort units):
    //  enc: xh1 [64][136] @0 ; h0 [64][72] @8704 ; zx [32][264] @8704
    //  VQ : cbA [32][264] @0 ; cbB [32][264] @8448
    //  dec: qbuf [64][264] @0 ; h3 [64][136] @16896 ; h4 [64][72] @0 ;
    //       xrb fp32 [64][132] @4608 (ushort offset)
    __shared__ __align__(16) ushort POOL[25600];
    __shared__ float scbn[NCODE];
    __shared__ int   midx[64];

    const int tid = threadIdx.x;
    const int b = blockIdx.y, s0 = blockIdx.x * 64;
    const size_t tok0 = (size_t)b * S_LEN + s0;
    const int lane = tid & 63, w = tid >> 6, r16 = lane & 15, g = lane >> 4;

    ushort* xh1 = POOL;            // stride 136
    ushort* h0  = POOL + 8704;     // stride 72
    ushort* zx  = POOL + 8704;     // stride 264 (32 rows)

    for (int i = tid; i < NCODE; i += 256) scbn[i] = cbn[i];

    { // stage x fp32 -> bf16 LDS [64][136]
        const float4* x4 = reinterpret_cast<const float4*>(x) + tok0 * 32;
#pragma unroll
        for (int it = 0; it < 8; ++it) {
            int idx = tid + it * 256;
            int t = idx >> 5, k4 = idx & 31;
            float4 v = x4[(size_t)t * 32 + k4];
            *reinterpret_cast<ushort4*>(&xh1[t * 136 + 4 * k4]) =
                make_ushort4(f2b(v.x), f2b(v.y), f2b(v.z), f2b(v.w));
        }
    }
    __syncthreads();

    const ushort* wb = wbf + (size_t)b * WB_STRIDE;

    // ---- e0: 128 -> 64, relu; wave owns cols [w*16, w*16+16)
    {
        const ushort* w0 = wb;
        short8v bf[4];
#pragma unroll
        for (int ks = 0; ks < 4; ++ks)
            bf[ks] = *reinterpret_cast<const short8v*>(
                w0 + (size_t)(w*16 + r16) * 128 + ks*32 + g*8);
        float bias = bb0[w*16 + r16];
#pragma unroll
        for (int tt = 0; tt < 4; ++tt) {
            float4v acc = (float4v){0.f, 0.f, 0.f, 0.f};
#pragma unroll
            for (int ks = 0; ks < 4; ++ks) {
                short8v a = *reinterpret_cast<const short8v*>(
                    &xh1[(tt*16 + r16) * 136 + ks*32 + g*8]);
                acc = __builtin_amdgcn_mfma_f32_16x16x32_bf16(a, bf[ks], acc, 0, 0, 0);
            }
#pragma unroll
            for (int reg = 0; reg < 4; ++reg)
                h0[(tt*16 + g*4 + reg) * 72 + w*16 + r16] =
                    f2b(fmaxf(acc[reg] + bias, 0.f));
        }
    }
    __syncthreads();

    // ---- e1: 64 -> 128, relu; wave cols [w*32, +32); h1 -> xh1
    {
        const ushort* w1 = wb + 8192;
#pragma unroll
        for (int nt = 0; nt < 2; ++nt) {
            int col0 = w*32 + nt*16;
            float bias = bb1[col0 + r16];
            short8v bf[2];
#pragma unroll
            for (int ks = 0; ks < 2; ++ks)
                bf[ks] = *reinterpret_cast<const short8v*>(
                    w1 + (size_t)(col0 + r16) * 64 + ks*32 + g*8);
#pragma unroll
            for (int tt = 0; tt < 4; ++tt) {
                float4v acc = (float4v){0.f, 0.f, 0.f, 0.f};
#pragma unroll
                for (int ks = 0; ks < 2; ++ks) {
                    short8v a = *reinterpret_cast<const short8v*>(
                        &h0[(tt*16 + r16) * 72 + ks*32 + g*8]);
                    acc = __builtin_amdgcn_mfma_f32_16x16x32_bf16(a, bf[ks], acc, 0, 0, 0);
                }
#pragma unroll
                for (int reg = 0; reg < 4; ++reg)
                    xh1[(tt*16 + g*4 + reg) * 136 + col0 + r16] =
                        f2b(fmaxf(acc[reg] + bias, 0.f));
            }
        }
    }
    __syncthreads();

    // ---- e2: 128 -> 256 in TWO 32-token halves via zx; az loaded per half
    const ushort* w2 = wb + 16384;
    short8v az[8];
#pragma unroll
    for (int half = 0; half < 2; ++half) {
#pragma unroll
        for (int nt = 0; nt < 4; ++nt) {
            int col0 = w*64 + nt*16;
            float bias = bb2[col0 + r16];
            short8v bf[4];
#pragma unroll
            for (int ks = 0; ks < 4; ++ks)
                bf[ks] = *reinterpret_cast<const short8v*>(
                    w2 + (size_t)(col0 + r16) * 128 + ks*32 + g*8);
#pragma unroll
            for (int tt2 = 0; tt2 < 2; ++tt2) {
                int tt = half*2 + tt2;
                float4v acc = (float4v){0.f, 0.f, 0.f, 0.f};
#pragma unroll
                for (int ks = 0; ks < 4; ++ks) {
                    short8v a = *reinterpret_cast<const short8v*>(
                        &xh1[(tt*16 + r16) * 136 + ks*32 + g*8]);
                    acc = __builtin_amdgcn_mfma_f32_16x16x32_bf16(a, bf[ks], acc, 0, 0, 0);
                }
#pragma unroll
                for (int reg = 0; reg < 4; ++reg)
                    zx[(tt2*16 + g*4 + reg) * 264 + col0 + r16] = f2b(acc[reg] + bias);
            }
        }
        __syncthreads();
        if ((w >> 1) == half) {
            int lrow = (w & 1)*16 + r16;
#pragma unroll
            for (int ks = 0; ks < 8; ++ks)
                az[ks] = *reinterpret_cast<const short8v*>(
                    &zx[lrow * 264 + ks*32 + g*8]);
        }
        __syncthreads();
    }

    // znorm per token (from az regs)
    float znorm = 0.f;
#pragma unroll
    for (int ks = 0; ks < 8; ++ks)
#pragma unroll
        for (int j = 0; j < 8; ++j) {
            float zv = b2f((ushort)az[ks][j]);
            znorm += zv * zv;
        }
    znorm += __shfl_xor(znorm, 16);
    znorm += __shfl_xor(znorm, 32);

    // ---- VQ: wave owns tokens [w*16, +16); argmin over 512 codes.
    float mv[4] = {1e30f, 1e30f, 1e30f, 1e30f};
    int   mi[4] = {0, 0, 0, 0};

    ushort* cbA = POOL;
    ushort* cbB = POOL + 8448;
    const int4* cb4 = reinterpret_cast<const int4*>(cbbf);
    const int k8 = tid & 31, cbase = tid >> 5;

    {
        int4 stg[4];
#pragma unroll
        for (int it = 0; it < 4; ++it)
            stg[it] = cb4[(size_t)(cbase + it*8) * 32 + k8];
#pragma unroll
        for (int it = 0; it < 4; ++it)
            *reinterpret_cast<int4*>(&cbA[(cbase + it*8) * 264 + k8*8]) = stg[it];
    }
    __syncthreads();

    for (int ch = 0; ch < 16; ++ch) {
        ushort* cur = (ch & 1) ? cbB : cbA;
        ushort* nxt = (ch & 1) ? cbA : cbB;
        int4 stg[4];
        if (ch < 15) {
#pragma unroll
            for (int it = 0; it < 4; ++it)
                stg[it] = cb4[(size_t)((ch+1)*32 + cbase + it*8) * 32 + k8];
        }
#pragma unroll
        for (int ct = 0; ct < 2; ++ct) {
            float4v d0 = (float4v){0.f, 0.f, 0.f, 0.f};
            float4v d1 = (float4v){0.f, 0.f, 0.f, 0.f};
#pragma unroll
            for (int ks = 0; ks < 8; ks += 2) {
                short8v b0 = *reinterpret_cast<const short8v*>(
                    &cur[(ct*16 + r16) * 264 + ks*32 + g*8]);
                short8v b1 = *reinterpret_cast<const short8v*>(
                    &cur[(ct*16 + r16) * 264 + (ks+1)*32 + g*8]);
                d0 = __builtin_amdgcn_mfma_f32_16x16x32_bf16(az[ks],   b0, d0, 0, 0, 0);
                d1 = __builtin_amdgcn_mfma_f32_16x16x32_bf16(az[ks+1], b1, d1, 0, 0, 0);
            }
            int c0 = ch*32 + ct*16 + r16;
            float cn = scbn[c0];
#pragma unroll
            for (int reg = 0; reg < 4; ++reg) {
                float dd = cn - 2.0f * (d0[reg] + d1[reg]);
                if (dd < mv[reg]) { mv[reg] = dd; mi[reg] = c0; }
            }
        }
        if (ch < 15) {
#pragma unroll
            for (int it = 0; it < 4; ++it)
                *reinterpret_cast<int4*>(&nxt[(cbase + it*8) * 264 + k8*8]) = stg[it];
        }
        __syncthreads();
    }

    // butterfly argmin (lex min == first-index)
#pragma unroll
    for (int m = 1; m <= 8; m <<= 1) {
#pragma unroll
        for (int reg = 0; reg < 4; ++reg) {
            float ov = __shfl_xor(mv[reg], m);
            int   oi = __shfl_xor(mi[reg], m);
            if (ov < mv[reg] || (ov == mv[reg] && oi < mi[reg])) {
                mv[reg] = ov; mi[reg] = oi;
            }
        }
    }
    if (r16 == 0) {
#pragma unroll
        for (int reg = 0; reg < 4; ++reg) midx[w*16 + g*4 + reg] = mi[reg];
    }
    __syncthreads();
    if (tid < 64) atomicAdd(&accg[1 + midx[tid]], 1.0f);

    // ---- dec gather q rows bf16 -> qbuf (POOL @0, stride 264) — issue early
    {
#pragma unroll
        for (int it = 0; it < 8; ++it) {
            int idx = tid + it * 256;
            int t = idx >> 5, kk = idx & 31;
            reinterpret_cast<int4*>(POOL)[t * 33 + kk] =
                cb4[(size_t)midx[t] * 32 + kk];
        }
    }

    // ---- sse = ||z||^2 + mv_min; wave shuffle-reduce, 1 atomic/wave
    float contrib = 0.f;
#pragma unroll
    for (int reg = 0; reg < 4; ++reg)
        if (r16 == g*4 + reg) contrib = znorm + mv[reg];
#pragma unroll
    for (int m = 1; m < 64; m <<= 1) contrib += __shfl_xor(contrib, m);
    if (lane == 0) atomicAdd(&accg[0], contrib);

    // ---- z_q = q (fp32 codebook gather), NT streamed
    float4v* zq4 = reinterpret_cast<float4v*>(zq) + tok0 * 64;
    const float4* cf4 = reinterpret_cast<const float4*>(cbf);
#pragma unroll
    for (int it = 0; it < 16; ++it) {
        int idx = tid + it * 256;
        int t = idx >> 6, k4 = idx & 63;
        float4 q = cf4[(size_t)midx[t] * 64 + k4];
        float4v ov = (float4v){q.x, q.y, q.z, q.w};
        __builtin_nontemporal_store(ov, &zq4[(size_t)t * 64 + k4]);
    }
    __syncthreads();   // qbuf complete

    // ================= decoder phase =================
    ushort* qbuf = POOL;           // [64][264]
    ushort* h3   = POOL + 16896;   // [64][136]
    ushort* h4   = POOL;           // [64][72]   (qbuf dead after d0)
    float*  xrb  = reinterpret_cast<float*>(POOL + 4608);  // [64][132] fp32

    // d0: 256 -> 128, relu; wave cols [w*32, +32)
    {
        const ushort* wD = wb + 49152;
#pragma unroll
        for (int nt = 0; nt < 2; ++nt) {
            int col0 = w*32 + nt*16;
            float bias = bb3[col0 + r16];
            short8v bf[8];
#pragma unroll
            for (int ks = 0; ks < 8; ++ks)
                bf[ks] = *reinterpret_cast<const short8v*>(
                    wD + (size_t)(col0 + r16) * 256 + ks*32 + g*8);
#pragma unroll
            for (int tt = 0; tt < 4; ++tt) {
                float4v acc = (float4v){0.f, 0.f, 0.f, 0.f};
#pragma unroll
                for (int ks = 0; ks < 8; ++ks) {
                    short8v a = *reinterpret_cast<const short8v*>(
                        &qbuf[(tt*16 + r16) * 264 + ks*32 + g*8]);
                    acc = __builtin_amdgcn_mfma_f32_16x16x32_bf16(a, bf[ks], acc, 0, 0, 0);
                }
#pragma unroll
                for (int reg = 0; reg < 4; ++reg)
                    h3[(tt*16 + g*4 + reg) * 136 + col0 + r16] =
                        f2b(fmaxf(acc[reg] + bias, 0.f));
            }
        }
    }
    __syncthreads();
    // d1: 128 -> 64, relu; wave cols [w*16, +16)
    {
        const ushort* wD = wb + 81920;
        float bias = bb4[w*16 + r16];
        short8v bf[4];
#pragma unroll
        for (int ks = 0; ks < 4; ++ks)
            bf[ks] = *reinterpret_cast<const short8v*>(
                wD + (size_t)(w*16 + r16) * 128 + ks*32 + g*8);
#pragma unroll
        for (int tt = 0; tt < 4; ++tt) {
            float4v acc = (float4v){0.f, 0.f, 0.f, 0.f};
#pragma unroll
            for (int ks = 0; ks < 4; ++ks) {
                short8v a = *reinterpret_cast<const short8v*>(
                    &h3[(tt*16 + r16) * 136 + ks*32 + g*8]);
                acc = __builtin_amdgcn_mfma_f32_16x16x32_bf16(a, bf[ks], acc, 0, 0, 0);
            }
#pragma unroll
            for (int reg = 0; reg < 4; ++reg)
                h4[(tt*16 + g*4 + reg) * 72 + w*16 + r16] =
                    f2b(fmaxf(acc[reg] + bias, 0.f));
        }
    }
    __syncthreads();
    // d2: 64 -> 128, sigmoid; wave cols [w*32, +32); -> xrb fp32
    {
        const ushort* wD = wb + 90112;
#pragma unroll
        for (int nt = 0; nt < 2; ++nt) {
            int col0 = w*32 + nt*16;
            float bias = bb5[col0 + r16];
            short8v bf[2];
#pragma unroll
            for (int ks = 0; ks < 2; ++ks)
                bf[ks] = *reinterpret_cast<const short8v*>(
                    wD + (size_t)(col0 + r16) * 64 + ks*32 + g*8);
#pragma unroll
            for (int tt = 0; tt < 4; ++tt) {
                float4v acc = (float4v){0.f, 0.f, 0.f, 0.f};
#pragma unroll
                for (int ks = 0; ks < 2; ++ks) {
                    short8v a = *reinterpret_cast<const short8v*>(
                        &h4[(tt*16 + r16) * 72 + ks*32 + g*8]);
                    acc = __builtin_amdgcn_mfma_f32_16x16x32_bf16(a, bf[ks], acc, 0, 0, 0);
                }
#pragma unroll
                for (int reg = 0; reg < 4; ++reg) {
                    float v = acc[reg] + bias;
                    xrb[(tt*16 + g*4 + reg) * 132 + col0 + r16] =
                        1.0f / (1.0f + expf(-v));
                }
            }
        }
    }
    __syncthreads();
    {   // vectorized store (xr base only 8B-aligned -> float2)
        float2v* xr2 = reinterpret_cast<float2v*>(xr) + tok0 * 64;
#pragma unroll
        for (int it = 0; it < 16; ++it) {
            int idx = tid + it * 256;
            int t = idx >> 6, k2 = idx & 63;
            float2v ov = (float2v){xrb[t * 132 + 2*k2], xrb[t * 132 + 2*k2 + 1]};
            __builtin_nontemporal_store(ov, &xr2[(size_t)t * 64 + k2]);
        }
    }
}

// ================= finalize scalars =================
__global__ __launch_bounds__(512)
void finalize_kernel(const float* __restrict__ acc, float* __restrict__ out_scal)
{
    __shared__ float red[512];
    int tid = threadIdx.x;
    float p = acc[1 + tid] * (1.0f / (float)NTOK);
    red[tid] = p * logf(p + 1e-10f);
    __syncthreads();
    for (int s = 256; s > 0; s >>= 1) {
        if (tid < s) red[tid] += red[tid + s];
        __syncthreads();
    }
    if (tid == 0) {
        out_scal[0] = 1.25f * (acc[0] * (1.0f / 33554432.0f)); // q_latent + 0.25*e_latent
        out_scal[1] = expf(-red[0]);
    }
}

// ================= launch =================
extern "C" void kernel_launch(void* const* d_in, const int* in_sizes, int n_in,
                              void* d_out, int out_size, void* d_ws, size_t ws_size,
                              hipStream_t stream)
{
    (void)in_sizes; (void)n_in; (void)out_size; (void)ws_size;
    const float* x     = (const float*)d_in[0];
    const float* adapt = (const float*)d_in[1];
    const float* bw[6]  = {(const float*)d_in[2],  (const float*)d_in[6],  (const float*)d_in[10],
                           (const float*)d_in[14], (const float*)d_in[18], (const float*)d_in[22]};
    const float* bbp[6] = {(const float*)d_in[3],  (const float*)d_in[7],  (const float*)d_in[11],
                           (const float*)d_in[15], (const float*)d_in[19], (const float*)d_in[23]};
    const float* aw[6]  = {(const float*)d_in[4],  (const float*)d_in[8],  (const float*)d_in[12],
                           (const float*)d_in[16], (const float*)d_in[20], (const float*)d_in[24]};
    const float* ab[6]  = {(const float*)d_in[5],  (const float*)d_in[9],  (const float*)d_in[13],
                           (const float*)d_in[17], (const float*)d_in[21], (const float*)d_in[25]};
    const float* cb = (const float*)d_in[26];

    char*   wsb  = (char*)d_ws;
    ushort* wbf  = (ushort*)(wsb + WSB_W);
    ushort* cbbf = (ushort*)(wsb + WSB_CB);
    float*  cbn  = (float*) (wsb + WSB_CBN);
    float*  acc  = (float*) (wsb + WSB_ACC);

    float*  out  = (float*)d_out;
    float*  zf   = out;              // z_q fp32
    float*  scal = out + OUT_SCAL;
    float*  xr   = out + OUT_XR;     // x_recon fp32

    hipMemsetAsync(acc, 0, 513 * sizeof(float), stream);

    WgenP p;
    const int loff[6]   = {0, 8192, 16384, 49152, 81920, 90112};
    const int bstart[7] = {0, 32, 64, 192, 320, 352, 384};
    for (int l = 0; l < 6; ++l) {
        p.bw[l] = bw[l]; p.aw[l] = aw[l]; p.ab[l] = ab[l]; p.loff[l] = loff[l];
    }
    for (int i = 0; i < 7; ++i) p.bstart[i] = bstart[i];

    wgen_all<<<384, 256, 0, stream>>>(p, adapt, wbf);
    cbprep_kernel<<<2, 256, 0, stream>>>(cb, cbn, cbbf);
    encdec_vq<<<dim3(64, 32), 256, 0, stream>>>(x, wbf,
                                                bbp[0], bbp[1], bbp[2],
                                                bbp[3], bbp[4], bbp[5],
                                                cbbf, cb, cbn, zf, xr, acc);
    finalize_kernel<<<1, 512, 0, stream>>>(acc, scal);
}